// Round 2
// baseline (15267.592 us; speedup 1.0000x reference)
//
#include <hip/hip_runtime.h>

// PyramidSampler: B=4 clouds of P=8192 pts, D=512 feats, scales (1.0, 0.5, 0.25).
// Scale 0.25's FPS indices are an exact prefix of scale 0.5's, so FPS runs once
// per batch for 4096 steps.
//
// R2 design: 256 threads/block (4 waves, 1/SIMD). All points mirrored in LDS by
// ORIGINAL index (96KB) so every thread fetches the new centroid directly ->
// single barrier per step (double-buffered wave keys). Points Morton-sorted
// (in-LDS bitonic) into 256 buckets of 32; each bucket keeps a register bbox
// and a cached (maxdist, argmax) key, and skips the distance update when the
// bbox lower bound (with conservative 5e-6 margin) proves min(dist,d)==dist
// for the whole bucket. dist values are always bit-exact vs the reference.

constexpr int kB  = 4;
constexpr int kP  = 8192;
constexpr int kD  = 512;
constexpr int kN1 = 4096;               // int(P*0.5)
constexpr int kN2 = 2048;               // int(P*0.25)
constexpr int kS  = kP + kN1 + kN2;     // 14336 rows per batch in fused output
constexpr int kT  = 256;                // fps threads: 4 waves
constexpr int kBk = kP / kT;            // 32 points per bucket

typedef unsigned long long u64;
typedef unsigned u32;

__global__ __launch_bounds__(kT)
void fps_kernel(const float* __restrict__ pos, int* __restrict__ idx_out) {
  const int b    = blockIdx.x;
  const int tid  = threadIdx.x;
  const int wave = tid >> 6;
  const int lane = tid & 63;
  const float* pb = pos + (size_t)b * kP * 3;
  int* idx = idx_out + b * kN1;

  __shared__ __attribute__((aligned(16))) float lds_pos[kP * 3];  // 96 KB, orig order
  __shared__ u32 lds_key[kP];                                     // 32 KB, morton|idx
  __shared__ float lds_bb[4][12];
  __shared__ u64 lds_wkey[2][4];

  // ---- 1) stage pos into LDS (coalesced float4) ----
  {
    const float4* src = reinterpret_cast<const float4*>(pb);
    float4* dst = reinterpret_cast<float4*>(lds_pos);
#pragma unroll
    for (int i = 0; i < (kP * 3 / 4) / kT; ++i)
      dst[tid + i * kT] = src[tid + i * kT];
  }
  __syncthreads();

  // ---- 2) cloud bbox (block reduce) ----
  float mn0 = 1e30f, mn1 = 1e30f, mn2 = 1e30f;
  float mx0 = -1e30f, mx1 = -1e30f, mx2 = -1e30f;
  for (int i = tid; i < kP; i += kT) {
    float x = lds_pos[3 * i], y = lds_pos[3 * i + 1], z = lds_pos[3 * i + 2];
    mn0 = fminf(mn0, x); mx0 = fmaxf(mx0, x);
    mn1 = fminf(mn1, y); mx1 = fmaxf(mx1, y);
    mn2 = fminf(mn2, z); mx2 = fmaxf(mx2, z);
  }
#pragma unroll
  for (int m = 32; m >= 1; m >>= 1) {
    mn0 = fminf(mn0, __shfl_xor(mn0, m, 64)); mx0 = fmaxf(mx0, __shfl_xor(mx0, m, 64));
    mn1 = fminf(mn1, __shfl_xor(mn1, m, 64)); mx1 = fmaxf(mx1, __shfl_xor(mx1, m, 64));
    mn2 = fminf(mn2, __shfl_xor(mn2, m, 64)); mx2 = fmaxf(mx2, __shfl_xor(mx2, m, 64));
  }
  if (lane == 0) {
    lds_bb[wave][0] = mn0; lds_bb[wave][1] = mn1; lds_bb[wave][2] = mn2;
    lds_bb[wave][3] = mx0; lds_bb[wave][4] = mx1; lds_bb[wave][5] = mx2;
  }
  __syncthreads();
#pragma unroll
  for (int w = 0; w < 4; ++w) {
    mn0 = fminf(mn0, lds_bb[w][0]); mn1 = fminf(mn1, lds_bb[w][1]); mn2 = fminf(mn2, lds_bb[w][2]);
    mx0 = fmaxf(mx0, lds_bb[w][3]); mx1 = fmaxf(mx1, lds_bb[w][4]); mx2 = fmaxf(mx2, lds_bb[w][5]);
  }

  // ---- 3) Morton keys: 18-bit code (6 bits/dim) << 13 | orig idx ----
  {
    const float i0 = 63.0f / fmaxf(mx0 - mn0, 1e-20f);
    const float i1 = 63.0f / fmaxf(mx1 - mn1, 1e-20f);
    const float i2 = 63.0f / fmaxf(mx2 - mn2, 1e-20f);
    for (int i = tid; i < kP; i += kT) {
      int qx = (int)((lds_pos[3 * i]     - mn0) * i0);
      int qy = (int)((lds_pos[3 * i + 1] - mn1) * i1);
      int qz = (int)((lds_pos[3 * i + 2] - mn2) * i2);
      qx = min(max(qx, 0), 63); qy = min(max(qy, 0), 63); qz = min(max(qz, 0), 63);
      u32 code = 0;
#pragma unroll
      for (int t = 0; t < 6; ++t)
        code |= (((u32)(qx >> t) & 1u) << (3 * t)) |
                (((u32)(qy >> t) & 1u) << (3 * t + 1)) |
                (((u32)(qz >> t) & 1u) << (3 * t + 2));
      lds_key[i] = (code << 13) | (u32)i;
    }
  }
  __syncthreads();

  // ---- 4) bitonic sort of 8192 u32 keys (keys unique: idx in low bits) ----
  for (int kk = 2; kk <= kP; kk <<= 1) {
    for (int j = kk >> 1; j > 0; j >>= 1) {
      const int mask = j - 1;
#pragma unroll
      for (int it = 0; it < (kP / 2) / kT; ++it) {
        int i = tid + it * kT;
        int a = ((i & ~mask) << 1) | (i & mask);
        int c = a | j;
        u32 x = lds_key[a], y = lds_key[c];
        bool up = ((a & kk) == 0);
        if ((x > y) == up) { lds_key[a] = y; lds_key[c] = x; }
      }
      __syncthreads();
    }
  }

  // ---- 5) bucket init: 32 sorted-consecutive points per thread ----
  int   oidx[kBk];
  float dist_[kBk];
  float lox = 1e30f, hix = -1e30f, loy = 1e30f, hiy = -1e30f, loz = 1e30f, hiz = -1e30f;
  int maxlo_init = 0;
  {
    const int base = tid * kBk;
#pragma unroll
    for (int k = 0; k < kBk; ++k) {
      int o = (int)(lds_key[base + k] & 8191u);
      oidx[k] = o;
      float x = lds_pos[3 * o], y = lds_pos[3 * o + 1], z = lds_pos[3 * o + 2];
      lox = fminf(lox, x); hix = fmaxf(hix, x);
      loy = fminf(loy, y); hiy = fmaxf(hiy, y);
      loz = fminf(loz, z); hiz = fmaxf(hiz, z);
      dist_[k] = 1e10f;
      maxlo_init = max(maxlo_init, 8191 - o);
    }
  }
  float cmax = 1e10f;                                   // cached bucket max dist
  u64 ckey = ((u64)__float_as_uint(1e10f) << 32) | (u32)maxlo_init;

  // ---- 6) main FPS loop: one barrier per step ----
  int far = 0;
  for (int s = 0; ; ++s) {
    if (tid == 0) idx[s] = far;
    if (s == kN1 - 1) break;

    const float cx = lds_pos[3 * far], cy = lds_pos[3 * far + 1], cz = lds_pos[3 * far + 2];

    // bbox lower bound on squared distance from c to any point in bucket
    float gx = fmaxf(fmaxf(lox - cx, cx - hix), 0.0f);
    float gy = fmaxf(fmaxf(loy - cy, cy - hiy), 0.0f);
    float gz = fmaxf(fmaxf(loz - cz, cz - hiz), 0.0f);
    float lb2 = gx * gx + gy * gy; lb2 = lb2 + gz * gz;

    u64 key;
    if (lb2 * 0.999995f >= cmax) {
      key = ckey;            // provably no dist in this bucket changes
    } else {
      float vbest = -1.0f; int lobest = 0;
      {
#pragma clang fp contract(off)
#pragma unroll
        for (int k = 0; k < kBk; ++k) {
          const int o3 = 3 * oidx[k];
          float dx = lds_pos[o3] - cx;
          float dy = lds_pos[o3 + 1] - cy;
          float dz = lds_pos[o3 + 2] - cz;
          float d = dx * dx + dy * dy;       // exact mul/add (XLA left fold)
          d = d + dz * dz;
          float dk = fminf(dist_[k], d);
          dist_[k] = dk;
          int lo = 8191 - oidx[k];
          bool gt = (dk > vbest) || (dk == vbest && lo > lobest);
          vbest  = gt ? dk : vbest;
          lobest = gt ? lo : lobest;
        }
      }
      key = ((u64)__float_as_uint(vbest) << 32) | (u32)lobest;
      ckey = key; cmax = vbest;
    }

    // wave argmax (packed u64: max dist, ties -> smallest orig idx)
#pragma unroll
    for (int m = 32; m >= 1; m >>= 1) {
      u64 o = __shfl_xor(key, m, 64);
      if (o > key) key = o;
    }
    if (lane == 0) lds_wkey[s & 1][wave] = key;
    __syncthreads();
    u64 b0 = lds_wkey[s & 1][0], b1 = lds_wkey[s & 1][1];
    u64 b2 = lds_wkey[s & 1][2], b3 = lds_wkey[s & 1][3];
    u64 m01 = b0 > b1 ? b0 : b1;
    u64 m23 = b2 > b3 ? b2 : b3;
    u64 mm  = m01 > m23 ? m01 : m23;
    far = 8191 - (int)(u32)(mm & 0xFFFFFFFFull);
  }
}

// ---------------------------------------------------------------------------
// Gather/assemble kernel (unchanged from R1, passed exactly).
// fused_x: [B][14336][512] then fused_p: [B][14336][3].
// ---------------------------------------------------------------------------
constexpr int kXRows     = kB * kS;                    // 57344
constexpr int kXBlocks   = kXRows / 2;                 // 28672
constexpr int kPosElems  = kB * kS * 3;                // 172032
constexpr int kPosBlocks = kPosElems / 256;            // 672

__device__ __forceinline__ int src_row(int b, int r, const int* __restrict__ idx) {
  int s;
  if (r < kP)            s = r;
  else if (r < kP + kN1) s = idx[b * kN1 + (r - kP)];
  else                   s = idx[b * kN1 + (r - kP - kN1)];
  return b * kP + s;
}

__global__ __launch_bounds__(256)
void gather_kernel(const float* __restrict__ x, const float* __restrict__ pos,
                   const int* __restrict__ idx, float* __restrict__ out) {
  const int blk = blockIdx.x;
  if (blk < kXBlocks) {
    const int row  = blk * 2 + (threadIdx.x >> 7);    // 2 rows per block
    const int lane = threadIdx.x & 127;               // 128 float4 per row
    const int b = row / kS;
    const int r = row - b * kS;
    const int sr = src_row(b, r, idx);
    const float4* src4 = reinterpret_cast<const float4*>(x + (size_t)sr * kD);
    float4* dst4       = reinterpret_cast<float4*>(out + (size_t)row * kD);
    dst4[lane] = src4[lane];
  } else {
    const int e = (blk - kXBlocks) * 256 + threadIdx.x;   // [0, kPosElems)
    const int row = e / 3;
    const int c   = e - row * 3;
    const int b = row / kS;
    const int r = row - b * kS;
    const int sr = src_row(b, r, idx);
    float* outp = out + (size_t)kB * kS * kD;
    outp[e] = pos[sr * 3 + c];
  }
}

extern "C" void kernel_launch(void* const* d_in, const int* in_sizes, int n_in,
                              void* d_out, int out_size, void* d_ws, size_t ws_size,
                              hipStream_t stream) {
  const float* x   = (const float*)d_in[0];   // [B*P, D] f32
  const float* pos = (const float*)d_in[1];   // [B*P, 3] f32
  // d_in[2] = batch_idx (int64): sorted equal-sized batches -> layout implied
  int* idx = (int*)d_ws;                      // [B][kN1] int32 = 64 KiB

  fps_kernel<<<kB, kT, 0, stream>>>(pos, idx);
  gather_kernel<<<kXBlocks + kPosBlocks, 256, 0, stream>>>(x, pos, idx, (float*)d_out);
}

// Round 4
// 8889.233 us; speedup vs baseline: 1.7175x; 1.7175x over previous
//
#include <hip/hip_runtime.h>

// PyramidSampler: B=4 clouds of P=8192 pts, D=512 feats, scales (1.0, 0.5, 0.25).
// Scale 0.25's FPS indices are an exact prefix of scale 0.5's, so FPS runs once
// per batch for 4096 steps.
//
// R3: points+dists REGISTER-resident (R1's win), Morton-sorted ownership with
// per-8-point sub-bucket bbox pruning (R2's win, without R2's scattered LDS
// reads). 256 threads (4 waves). One barrier per step. Packed argmax key
// [dist:32|lo:13|sp:13] so the winner key addresses a sorted-order LDS coord
// mirror for the centroid fetch. dist math is bit-exact vs XLA (no fma,
// (dx^2+dy^2)+dz^2 fold); prune skips only when min(dist,d)==dist is provable
// for the whole sub-bucket (lb2*0.999995 >= subbucket max dist).

constexpr int kB   = 4;
constexpr int kP   = 8192;
constexpr int kD   = 512;
constexpr int kN1  = 4096;              // int(P*0.5)
constexpr int kN2  = 2048;              // int(P*0.25)
constexpr int kS   = kP + kN1 + kN2;    // 14336 rows per batch
constexpr int kT   = 256;               // fps threads: 4 waves
constexpr int kPts = kP / kT;           // 32 points per thread
constexpr int kG   = 4;                 // sub-buckets per thread
constexpr int kGp  = kPts / kG;         // 8 points per sub-bucket

typedef unsigned long long u64;
typedef unsigned u32;

__global__ __launch_bounds__(kT, 1)
void fps_kernel(const float* __restrict__ pos, int* __restrict__ idx_out) {
  const int b    = blockIdx.x;
  const int tid  = threadIdx.x;
  const int wave = tid >> 6;
  const int lane = tid & 63;
  const float* pb = pos + (size_t)b * kP * 3;
  int* idx = idx_out + b * kN1;

  __shared__ __attribute__((aligned(16))) float lds_pos[kP * 3]; // orig, then sorted
  __shared__ u32 lds_key[kP];
  __shared__ float lds_bb[4][6];
  __shared__ u64 lds_wkey[2][4];
  __shared__ float lds_c0[3];

  // ---- 1) stage pos into LDS (orig order, coalesced float4) ----
  {
    const float4* src = reinterpret_cast<const float4*>(pb);
    float4* dst = reinterpret_cast<float4*>(lds_pos);
#pragma unroll
    for (int i = 0; i < (kP * 3 / 4) / kT; ++i)
      dst[tid + i * kT] = src[tid + i * kT];
  }
  __syncthreads();

  // ---- 2) cloud bbox (block reduce) ----
  float mn0 = 1e30f, mn1 = 1e30f, mn2 = 1e30f;
  float mx0 = -1e30f, mx1 = -1e30f, mx2 = -1e30f;
  for (int i = tid; i < kP; i += kT) {
    float x = lds_pos[3 * i], y = lds_pos[3 * i + 1], z = lds_pos[3 * i + 2];
    mn0 = fminf(mn0, x); mx0 = fmaxf(mx0, x);
    mn1 = fminf(mn1, y); mx1 = fmaxf(mx1, y);
    mn2 = fminf(mn2, z); mx2 = fmaxf(mx2, z);
  }
#pragma unroll
  for (int m = 32; m >= 1; m >>= 1) {
    mn0 = fminf(mn0, __shfl_xor(mn0, m, 64)); mx0 = fmaxf(mx0, __shfl_xor(mx0, m, 64));
    mn1 = fminf(mn1, __shfl_xor(mn1, m, 64)); mx1 = fmaxf(mx1, __shfl_xor(mx1, m, 64));
    mn2 = fminf(mn2, __shfl_xor(mn2, m, 64)); mx2 = fmaxf(mx2, __shfl_xor(mx2, m, 64));
  }
  if (lane == 0) {
    lds_bb[wave][0] = mn0; lds_bb[wave][1] = mn1; lds_bb[wave][2] = mn2;
    lds_bb[wave][3] = mx0; lds_bb[wave][4] = mx1; lds_bb[wave][5] = mx2;
  }
  __syncthreads();
#pragma unroll
  for (int w = 0; w < 4; ++w) {
    mn0 = fminf(mn0, lds_bb[w][0]); mn1 = fminf(mn1, lds_bb[w][1]); mn2 = fminf(mn2, lds_bb[w][2]);
    mx0 = fmaxf(mx0, lds_bb[w][3]); mx1 = fmaxf(mx1, lds_bb[w][4]); mx2 = fmaxf(mx2, lds_bb[w][5]);
  }

  // ---- 3) Morton keys: 18-bit code << 13 | orig idx ----
  {
    const float i0 = 63.0f / fmaxf(mx0 - mn0, 1e-20f);
    const float i1 = 63.0f / fmaxf(mx1 - mn1, 1e-20f);
    const float i2 = 63.0f / fmaxf(mx2 - mn2, 1e-20f);
    for (int i = tid; i < kP; i += kT) {
      int qx = (int)((lds_pos[3 * i]     - mn0) * i0);
      int qy = (int)((lds_pos[3 * i + 1] - mn1) * i1);
      int qz = (int)((lds_pos[3 * i + 2] - mn2) * i2);
      qx = min(max(qx, 0), 63); qy = min(max(qy, 0), 63); qz = min(max(qz, 0), 63);
      u32 code = 0;
#pragma unroll
      for (int t = 0; t < 6; ++t)
        code |= (((u32)(qx >> t) & 1u) << (3 * t)) |
                (((u32)(qy >> t) & 1u) << (3 * t + 1)) |
                (((u32)(qz >> t) & 1u) << (3 * t + 2));
      lds_key[i] = (code << 13) | (u32)i;
    }
  }
  __syncthreads();

  // ---- 4) bitonic sort of 8192 u32 keys ----
  for (int kk = 2; kk <= kP; kk <<= 1) {
    for (int j = kk >> 1; j > 0; j >>= 1) {
      const int mask = j - 1;
#pragma unroll
      for (int it = 0; it < (kP / 2) / kT; ++it) {
        int i = tid + it * kT;
        int a = ((i & ~mask) << 1) | (i & mask);
        int c = a | j;
        u32 x = lds_key[a], y = lds_key[c];
        bool up = ((a & kk) == 0);
        if ((x > y) == up) { lds_key[a] = y; lds_key[c] = x; }
      }
      __syncthreads();
    }
  }

  // ---- 5) gather 32 points/thread into REGISTERS (sorted order) ----
  float px[kPts], py[kPts], pz[kPts], dist_[kPts];
  int lo_[kPts];
  {
    const int base = tid * kPts;
#pragma unroll
    for (int m = 0; m < kPts; ++m) {
      int o = (int)(lds_key[base + m] & 8191u);
      px[m] = lds_pos[3 * o];
      py[m] = lds_pos[3 * o + 1];
      pz[m] = lds_pos[3 * o + 2];
      lo_[m] = 8191 - o;
      dist_[m] = 1e10f;
      if (o == 0) { lds_c0[0] = px[m]; lds_c0[1] = py[m]; lds_c0[2] = pz[m]; }
    }
  }
  __syncthreads();   // all gather-reads of lds_pos done before overwrite

  // ---- 6) write sorted-order coord mirror (for centroid fetch by sp) ----
  {
    const int base3 = tid * kPts * 3;
#pragma unroll
    for (int m = 0; m < kPts; ++m) {
      lds_pos[base3 + 3 * m]     = px[m];
      lds_pos[base3 + 3 * m + 1] = py[m];
      lds_pos[base3 + 3 * m + 2] = pz[m];
    }
  }

  // ---- 7) sub-bucket bboxes + cached keys ----
  float blx[kG], bhx[kG], bly[kG], bhy[kG], blz[kG], bhz[kG];
  u64 cku[kG];
#pragma unroll
  for (int g = 0; g < kG; ++g) {
    float lx = 1e30f, hx = -1e30f, ly = 1e30f, hy = -1e30f, lz = 1e30f, hz = -1e30f;
    u32 best = 0;
#pragma unroll
    for (int k = 0; k < kGp; ++k) {
      const int m = g * kGp + k;
      lx = fminf(lx, px[m]); hx = fmaxf(hx, px[m]);
      ly = fminf(ly, py[m]); hy = fmaxf(hy, py[m]);
      lz = fminf(lz, pz[m]); hz = fmaxf(hz, pz[m]);
      u32 losp = ((u32)lo_[m] << 13) | (u32)(tid * kPts + m);
      best = best > losp ? best : losp;
    }
    blx[g] = lx; bhx[g] = hx; bly[g] = ly; bhy[g] = hy; blz[g] = lz; bhz[g] = hz;
    cku[g] = ((u64)__float_as_uint(1e10f) << 26) | best;
  }
  __syncthreads();   // sorted mirror + lds_c0 visible

  // ---- 8) main FPS loop: one barrier per step ----
  float cx = lds_c0[0], cy = lds_c0[1], cz = lds_c0[2];
  int far = 0;
  for (int s = 0; ; ++s) {
    if (tid == 0) idx[s] = far;
    if (s == kN1 - 1) break;

    u64 tk = 0;
#pragma unroll
    for (int g = 0; g < kG; ++g) {
      float gx = fmaxf(fmaxf(blx[g] - cx, cx - bhx[g]), 0.0f);
      float gy = fmaxf(fmaxf(bly[g] - cy, cy - bhy[g]), 0.0f);
      float gz = fmaxf(fmaxf(blz[g] - cz, cz - bhz[g]), 0.0f);
      float lb2 = gx * gx + gy * gy; lb2 = lb2 + gz * gz;
      float cv = __uint_as_float((u32)(cku[g] >> 26));
      if (!(lb2 * 0.999995f >= cv)) {
        float vb = -1.0f; u32 lsb = 0;
        {
#pragma clang fp contract(off)
#pragma unroll
          for (int k = 0; k < kGp; ++k) {
            const int m = g * kGp + k;
            float dx = px[m] - cx;
            float dy = py[m] - cy;
            float dz = pz[m] - cz;
            float d = dx * dx + dy * dy;   // exact mul/add (XLA left fold)
            d = d + dz * dz;
            float dk = fminf(dist_[m], d);
            dist_[m] = dk;
            u32 losp = ((u32)lo_[m] << 13) | (u32)(tid * kPts + m);
            bool gt = (dk > vb) || (dk == vb && losp > lsb);
            vb  = gt ? dk : vb;
            lsb = gt ? losp : lsb;
          }
        }
        cku[g] = ((u64)__float_as_uint(vb) << 26) | lsb;
      }
      tk = tk > cku[g] ? tk : cku[g];
    }

    // wave argmax on packed u64 (ties impossible: lo unique)
#pragma unroll
    for (int m = 32; m >= 1; m >>= 1) {
      u64 o = __shfl_xor(tk, m, 64);
      if (o > tk) tk = o;
    }
    if (lane == 0) lds_wkey[s & 1][wave] = tk;
    __syncthreads();
    u64 k0 = lds_wkey[s & 1][0], k1 = lds_wkey[s & 1][1];
    u64 k2 = lds_wkey[s & 1][2], k3 = lds_wkey[s & 1][3];
    u64 m01 = k0 > k1 ? k0 : k1;
    u64 m23 = k2 > k3 ? k2 : k3;
    u64 mm  = m01 > m23 ? m01 : m23;
    far = 8191 - (int)((mm >> 13) & 0x1FFFu);
    const int sp = (int)(mm & 0x1FFFu);
    cx = lds_pos[3 * sp]; cy = lds_pos[3 * sp + 1]; cz = lds_pos[3 * sp + 2];
  }
}

// ---------------------------------------------------------------------------
// Gather/assemble kernel (unchanged — proven bit-exact).
// fused_x: [B][14336][512] then fused_p: [B][14336][3].
// ---------------------------------------------------------------------------
constexpr int kXRows     = kB * kS;                    // 57344
constexpr int kXBlocks   = kXRows / 2;                 // 28672
constexpr int kPosElems  = kB * kS * 3;                // 172032
constexpr int kPosBlocks = kPosElems / 256;            // 672

__device__ __forceinline__ int src_row(int b, int r, const int* __restrict__ idx) {
  int s;
  if (r < kP)            s = r;
  else if (r < kP + kN1) s = idx[b * kN1 + (r - kP)];
  else                   s = idx[b * kN1 + (r - kP - kN1)];
  return b * kP + s;
}

__global__ __launch_bounds__(256)
void gather_kernel(const float* __restrict__ x, const float* __restrict__ pos,
                   const int* __restrict__ idx, float* __restrict__ out) {
  const int blk = blockIdx.x;
  if (blk < kXBlocks) {
    const int row  = blk * 2 + (threadIdx.x >> 7);    // 2 rows per block
    const int lane = threadIdx.x & 127;               // 128 float4 per row
    const int b = row / kS;
    const int r = row - b * kS;
    const int sr = src_row(b, r, idx);
    const float4* src4 = reinterpret_cast<const float4*>(x + (size_t)sr * kD);
    float4* dst4       = reinterpret_cast<float4*>(out + (size_t)row * kD);
    dst4[lane] = src4[lane];
  } else {
    const int e = (blk - kXBlocks) * 256 + threadIdx.x;   // [0, kPosElems)
    const int row = e / 3;
    const int c   = e - row * 3;
    const int b = row / kS;
    const int r = row - b * kS;
    const int sr = src_row(b, r, idx);
    float* outp = out + (size_t)kB * kS * kD;
    outp[e] = pos[sr * 3 + c];
  }
}

extern "C" void kernel_launch(void* const* d_in, const int* in_sizes, int n_in,
                              void* d_out, int out_size, void* d_ws, size_t ws_size,
                              hipStream_t stream) {
  const float* x   = (const float*)d_in[0];   // [B*P, D] f32
  const float* pos = (const float*)d_in[1];   // [B*P, 3] f32
  // d_in[2] = batch_idx (int64): sorted equal-sized batches -> layout implied
  int* idx = (int*)d_ws;                      // [B][kN1] int32 = 64 KiB

  fps_kernel<<<kB, kT, 0, stream>>>(pos, idx);
  gather_kernel<<<kXBlocks + kPosBlocks, 256, 0, stream>>>(x, pos, idx, (float*)d_out);
}

// Round 5
// 7536.768 us; speedup vs baseline: 2.0257x; 1.1794x over previous
//
#include <hip/hip_runtime.h>

// PyramidSampler: B=4 clouds of P=8192 pts, D=512 feats, scales (1.0, 0.5, 0.25).
// Scale 0.25's FPS indices are an exact prefix of scale 0.5's -> one 4096-step
// FPS per batch.
//
// R4: attack the per-step latency chain (R1 and R3 both ~5300 cyc/step despite
// different update costs -> update VALU is not the bottleneck):
//  - 512 threads (8 waves), 16 pts/thread: ~130 live VGPRs, kills R3's spill
//    (R3 needed ~210, got 132 -> ~80 dwords scratch on the hot path).
//  - DPP butterfly (quad_perm/mirror/bcast) replaces u64 __shfl_xor: 6 stages
//    at VALU speed instead of 12 ds_bpermute @ ~120 cyc LDS latency.
//  - winner coords carried THROUGH the reduction (key = dist,lo1,x,y,z), so no
//    dependent centroid LDS fetch and no 96KB sorted mirror.
// Kept bit-exact: no fma ((dx^2+dy^2)+dz^2 left fold), min-update, argmax ties
// -> smallest original index (lo1 = 8192-o, max lo1 wins), prune only when
// lb2*0.999995 >= cached bucket max (proven absmax 0.0 in R2/R3).

constexpr int kB   = 4;
constexpr int kP   = 8192;
constexpr int kD   = 512;
constexpr int kN1  = 4096;              // int(P*0.5)
constexpr int kN2  = 2048;              // int(P*0.25)
constexpr int kS   = kP + kN1 + kN2;    // 14336 rows per batch
constexpr int kT   = 512;               // 8 waves
constexpr int kW   = kT / 64;           // 8
constexpr int kPts = kP / kT;           // 16 points per thread
constexpr int kG   = 2;                 // sub-buckets per thread
constexpr int kGp  = kPts / kG;         // 8 points per sub-bucket

typedef unsigned long long u64;
typedef unsigned u32;

template <int CTRL>
__device__ __forceinline__ u32 dpp1(u32 v) {
  return (u32)__builtin_amdgcn_update_dpp((int)v, (int)v, CTRL, 0xF, 0xF, false);
}

// combined argmax key: (dist f32, lo1 u32 tie-break, coords as bits)
__device__ __forceinline__ void keymax(float& d, u32& l, u32& x, u32& y, u32& z,
                                       float od, u32 ol, u32 ox, u32 oy, u32 oz) {
  bool t = (od > d) || (od == d && ol > l);
  d = t ? od : d; l = t ? ol : l;
  x = t ? ox : x; y = t ? oy : y; z = t ? oz : z;
}

// one DPP butterfly/broadcast stage of the wave reduction (old=own so
// non-receiving lanes on bcast stages combine with self = no-op)
#define DPP_STAGE(CTRL)                                                     \
  {                                                                         \
    u32 pd = dpp1<CTRL>(__float_as_uint(kd));                               \
    u32 pl = dpp1<CTRL>(kl);                                                \
    u32 qx = dpp1<CTRL>(kx);                                                \
    u32 qy = dpp1<CTRL>(ky);                                                \
    u32 qz = dpp1<CTRL>(kz);                                                \
    keymax(kd, kl, kx, ky, kz, __uint_as_float(pd), pl, qx, qy, qz);        \
  }

__global__ __launch_bounds__(kT, 2)
void fps_kernel(const float* __restrict__ pos, int* __restrict__ idx_out) {
  const int b    = blockIdx.x;
  const int tid  = threadIdx.x;
  const int wave = tid >> 6;
  const int lane = tid & 63;
  const float* pb = pos + (size_t)b * kP * 3;
  int* idx = idx_out + b * kN1;

  __shared__ __attribute__((aligned(16))) float lds_pos[kP * 3];  // 96 KB (setup only)
  __shared__ u32 lds_key[kP];                                     // 32 KB (setup only)
  __shared__ float lds_bb[kW][6];
  __shared__ __attribute__((aligned(16))) u32 wslot[2][kW][8];    // [par][wave][d,lo1,x,y,z,...]
  __shared__ float lds_c0[3];

  // ---- 1) stage pos into LDS (orig order, coalesced float4) ----
  {
    const float4* src = reinterpret_cast<const float4*>(pb);
    float4* dst = reinterpret_cast<float4*>(lds_pos);
#pragma unroll
    for (int i = 0; i < (kP * 3 / 4) / kT; ++i)        // 12 iters
      dst[tid + i * kT] = src[tid + i * kT];
  }
  __syncthreads();

  // ---- 2) cloud bbox (block reduce; setup-only, shfl latency OK) ----
  float mn0 = 1e30f, mn1 = 1e30f, mn2 = 1e30f;
  float mx0 = -1e30f, mx1 = -1e30f, mx2 = -1e30f;
  for (int i = tid; i < kP; i += kT) {
    float x = lds_pos[3 * i], y = lds_pos[3 * i + 1], z = lds_pos[3 * i + 2];
    mn0 = fminf(mn0, x); mx0 = fmaxf(mx0, x);
    mn1 = fminf(mn1, y); mx1 = fmaxf(mx1, y);
    mn2 = fminf(mn2, z); mx2 = fmaxf(mx2, z);
  }
#pragma unroll
  for (int m = 32; m >= 1; m >>= 1) {
    mn0 = fminf(mn0, __shfl_xor(mn0, m, 64)); mx0 = fmaxf(mx0, __shfl_xor(mx0, m, 64));
    mn1 = fminf(mn1, __shfl_xor(mn1, m, 64)); mx1 = fmaxf(mx1, __shfl_xor(mx1, m, 64));
    mn2 = fminf(mn2, __shfl_xor(mn2, m, 64)); mx2 = fmaxf(mx2, __shfl_xor(mx2, m, 64));
  }
  if (lane == 0) {
    lds_bb[wave][0] = mn0; lds_bb[wave][1] = mn1; lds_bb[wave][2] = mn2;
    lds_bb[wave][3] = mx0; lds_bb[wave][4] = mx1; lds_bb[wave][5] = mx2;
  }
  __syncthreads();
#pragma unroll
  for (int w = 0; w < kW; ++w) {
    mn0 = fminf(mn0, lds_bb[w][0]); mn1 = fminf(mn1, lds_bb[w][1]); mn2 = fminf(mn2, lds_bb[w][2]);
    mx0 = fmaxf(mx0, lds_bb[w][3]); mx1 = fmaxf(mx1, lds_bb[w][4]); mx2 = fmaxf(mx2, lds_bb[w][5]);
  }

  // ---- 3) Morton keys: 18-bit code << 13 | orig idx ----
  {
    const float i0 = 63.0f / fmaxf(mx0 - mn0, 1e-20f);
    const float i1 = 63.0f / fmaxf(mx1 - mn1, 1e-20f);
    const float i2 = 63.0f / fmaxf(mx2 - mn2, 1e-20f);
    for (int i = tid; i < kP; i += kT) {
      int qx = (int)((lds_pos[3 * i]     - mn0) * i0);
      int qy = (int)((lds_pos[3 * i + 1] - mn1) * i1);
      int qz = (int)((lds_pos[3 * i + 2] - mn2) * i2);
      qx = min(max(qx, 0), 63); qy = min(max(qy, 0), 63); qz = min(max(qz, 0), 63);
      u32 code = 0;
#pragma unroll
      for (int t = 0; t < 6; ++t)
        code |= (((u32)(qx >> t) & 1u) << (3 * t)) |
                (((u32)(qy >> t) & 1u) << (3 * t + 1)) |
                (((u32)(qz >> t) & 1u) << (3 * t + 2));
      lds_key[i] = (code << 13) | (u32)i;
    }
  }
  __syncthreads();

  // ---- 4) bitonic sort of 8192 u32 keys (unique: idx in low bits) ----
  for (int kk = 2; kk <= kP; kk <<= 1) {
    for (int j = kk >> 1; j > 0; j >>= 1) {
      const int mask = j - 1;
#pragma unroll
      for (int it = 0; it < (kP / 2) / kT; ++it) {     // 8 iters
        int i = tid + it * kT;
        int a = ((i & ~mask) << 1) | (i & mask);
        int c = a | j;
        u32 x = lds_key[a], y = lds_key[c];
        bool up = ((a & kk) == 0);
        if ((x > y) == up) { lds_key[a] = y; lds_key[c] = x; }
      }
      __syncthreads();
    }
  }

  // ---- 5) gather 16 pts/thread into registers (sorted order) ----
  float px[kPts], py[kPts], pz[kPts], dist_[kPts];
  u32 lo1_[kPts];                       // 8192 - orig_idx (unique, >0)
  {
    const int base = tid * kPts;
#pragma unroll
    for (int m = 0; m < kPts; ++m) {
      int o = (int)(lds_key[base + m] & 8191u);
      px[m] = lds_pos[3 * o];
      py[m] = lds_pos[3 * o + 1];
      pz[m] = lds_pos[3 * o + 2];
      lo1_[m] = (u32)(8192 - o);
      dist_[m] = 1e10f;
      if (o == 0) { lds_c0[0] = px[m]; lds_c0[1] = py[m]; lds_c0[2] = pz[m]; }
    }
  }

  // ---- 6) sub-bucket bboxes + cached keys (vb, lo1, winner coords) ----
  float blx[kG], bhx[kG], bly[kG], bhy[kG], blz[kG], bhz[kG];
  float cgd[kG]; u32 cgl[kG], cgx[kG], cgy[kG], cgz[kG];
#pragma unroll
  for (int g = 0; g < kG; ++g) {
    float lx = 1e30f, hx = -1e30f, ly = 1e30f, hy = -1e30f, lz = 1e30f, hz = -1e30f;
    u32 lob = 0, wx = 0, wy = 0, wz = 0;
#pragma unroll
    for (int k = 0; k < kGp; ++k) {
      const int m = g * kGp + k;
      lx = fminf(lx, px[m]); hx = fmaxf(hx, px[m]);
      ly = fminf(ly, py[m]); hy = fmaxf(hy, py[m]);
      lz = fminf(lz, pz[m]); hz = fmaxf(hz, pz[m]);
      bool t = lo1_[m] > lob;           // all dists equal (1e10) -> max lo1 wins
      lob = t ? lo1_[m] : lob;
      wx = t ? __float_as_uint(px[m]) : wx;
      wy = t ? __float_as_uint(py[m]) : wy;
      wz = t ? __float_as_uint(pz[m]) : wz;
    }
    blx[g] = lx; bhx[g] = hx; bly[g] = ly; bhy[g] = hy; blz[g] = lz; bhz[g] = hz;
    cgd[g] = 1e10f; cgl[g] = lob; cgx[g] = wx; cgy[g] = wy; cgz[g] = wz;
  }
  __syncthreads();                      // lds_c0 visible

  // ---- 7) main FPS loop: one barrier per step ----
  float cx = lds_c0[0], cy = lds_c0[1], cz = lds_c0[2];
  int far = 0;
  for (int s = 0; ; ++s) {
    if (tid == 0) idx[s] = far;
    if (s == kN1 - 1) break;

#pragma unroll
    for (int g = 0; g < kG; ++g) {
      float gx = fmaxf(fmaxf(blx[g] - cx, cx - bhx[g]), 0.0f);
      float gy = fmaxf(fmaxf(bly[g] - cy, cy - bhy[g]), 0.0f);
      float gz = fmaxf(fmaxf(blz[g] - cz, cz - bhz[g]), 0.0f);
      float lb2 = gx * gx + gy * gy; lb2 = lb2 + gz * gz;
      if (!(lb2 * 0.999995f >= cgd[g])) {
        {
#pragma clang fp contract(off)
#pragma unroll
          for (int k = 0; k < kGp; ++k) {
            const int m = g * kGp + k;
            float dx = px[m] - cx;
            float dy = py[m] - cy;
            float dz = pz[m] - cz;
            float d = dx * dx + dy * dy;   // exact mul/add (XLA left fold)
            d = d + dz * dz;
            dist_[m] = fminf(dist_[m], d);
          }
        }
        float vb = dist_[g * kGp];
#pragma unroll
        for (int k = 1; k < kGp; ++k) vb = fmaxf(vb, dist_[g * kGp + k]);
        u32 lob = 0;
#pragma unroll
        for (int k = 0; k < kGp; ++k) {
          const int m = g * kGp + k;
          u32 c = (dist_[m] == vb) ? lo1_[m] : 0u;   // lo1 > 0 always
          lob = lob > c ? lob : c;
        }
        u32 wx = cgx[g], wy = cgy[g], wz = cgz[g];
#pragma unroll
        for (int k = 0; k < kGp; ++k) {
          const int m = g * kGp + k;
          bool t = (lo1_[m] == lob);                 // unique match
          wx = t ? __float_as_uint(px[m]) : wx;
          wy = t ? __float_as_uint(py[m]) : wy;
          wz = t ? __float_as_uint(pz[m]) : wz;
        }
        cgd[g] = vb; cgl[g] = lob; cgx[g] = wx; cgy[g] = wy; cgz[g] = wz;
      }
    }

    // thread key = max over its 2 cached group keys
    float kd = cgd[0]; u32 kl = cgl[0], kx = cgx[0], ky = cgy[0], kz = cgz[0];
    keymax(kd, kl, kx, ky, kz, cgd[1], cgl[1], cgx[1], cgy[1], cgz[1]);

    // DPP wave reduction: xor1, xor2, xor7, xor15 (row max everywhere),
    // then bcast15 + bcast31 (global max lands in lanes 48..63)
    DPP_STAGE(0xB1);   // quad_perm [1,0,3,2]
    DPP_STAGE(0x4E);   // quad_perm [2,3,0,1]
    DPP_STAGE(0x141);  // row_half_mirror
    DPP_STAGE(0x140);  // row_mirror
    DPP_STAGE(0x142);  // row_bcast15
    DPP_STAGE(0x143);  // row_bcast31

    if (lane == 63) {
      u32* slot = &wslot[s & 1][wave][0];
      slot[0] = __float_as_uint(kd); slot[1] = kl;
      slot[2] = kx; slot[3] = ky; slot[4] = kz;
    }
    __syncthreads();

    // cross-wave combine: 8 broadcast reads + static tree
    const u32 (*sl)[8] = wslot[s & 1];
    float sd[kW]; u32 sv[kW], sx[kW], sy[kW], sz[kW];
#pragma unroll
    for (int w = 0; w < kW; ++w) {
      uint4 q = *reinterpret_cast<const uint4*>(&sl[w][0]);
      sd[w] = __uint_as_float(q.x); sv[w] = q.y;
      sx[w] = q.z; sy[w] = q.w; sz[w] = sl[w][4];
    }
#pragma unroll
    for (int st = 1; st < kW; st <<= 1)
#pragma unroll
      for (int w = 0; w < kW; w += 2 * st)
        keymax(sd[w], sv[w], sx[w], sy[w], sz[w],
               sd[w + st], sv[w + st], sx[w + st], sy[w + st], sz[w + st]);

    far = 8192 - (int)sv[0];
    cx = __uint_as_float(sx[0]);
    cy = __uint_as_float(sy[0]);
    cz = __uint_as_float(sz[0]);
  }
}

// ---------------------------------------------------------------------------
// Gather/assemble kernel (unchanged — proven bit-exact).
// fused_x: [B][14336][512] then fused_p: [B][14336][3].
// ---------------------------------------------------------------------------
constexpr int kXRows     = kB * kS;                    // 57344
constexpr int kXBlocks   = kXRows / 2;                 // 28672
constexpr int kPosElems  = kB * kS * 3;                // 172032
constexpr int kPosBlocks = kPosElems / 256;            // 672

__device__ __forceinline__ int src_row(int b, int r, const int* __restrict__ idx) {
  int s;
  if (r < kP)            s = r;
  else if (r < kP + kN1) s = idx[b * kN1 + (r - kP)];
  else                   s = idx[b * kN1 + (r - kP - kN1)];
  return b * kP + s;
}

__global__ __launch_bounds__(256)
void gather_kernel(const float* __restrict__ x, const float* __restrict__ pos,
                   const int* __restrict__ idx, float* __restrict__ out) {
  const int blk = blockIdx.x;
  if (blk < kXBlocks) {
    const int row  = blk * 2 + (threadIdx.x >> 7);    // 2 rows per block
    const int lane = threadIdx.x & 127;               // 128 float4 per row
    const int b = row / kS;
    const int r = row - b * kS;
    const int sr = src_row(b, r, idx);
    const float4* src4 = reinterpret_cast<const float4*>(x + (size_t)sr * kD);
    float4* dst4       = reinterpret_cast<float4*>(out + (size_t)row * kD);
    dst4[lane] = src4[lane];
  } else {
    const int e = (blk - kXBlocks) * 256 + threadIdx.x;   // [0, kPosElems)
    const int row = e / 3;
    const int c   = e - row * 3;
    const int b = row / kS;
    const int r = row - b * kS;
    const int sr = src_row(b, r, idx);
    float* outp = out + (size_t)kB * kS * kD;
    outp[e] = pos[sr * 3 + c];
  }
}

extern "C" void kernel_launch(void* const* d_in, const int* in_sizes, int n_in,
                              void* d_out, int out_size, void* d_ws, size_t ws_size,
                              hipStream_t stream) {
  const float* x   = (const float*)d_in[0];   // [B*P, D] f32
  const float* pos = (const float*)d_in[1];   // [B*P, 3] f32
  // d_in[2] = batch_idx (int64): sorted equal-sized batches -> layout implied
  int* idx = (int*)d_ws;                      // [B][kN1] int32 = 64 KiB

  fps_kernel<<<kB, kT, 0, stream>>>(pos, idx);
  gather_kernel<<<kXBlocks + kPosBlocks, 256, 0, stream>>>(x, pos, idx, (float*)d_out);
}